// Round 1
// baseline (1043.951 us; speedup 1.0000x reference)
//
#include <hip/hip_runtime.h>

#define N_NODES 100000
#define N_EDGES 1600000
#define NFEAT   128
#define NGRAPH  256
#define NACT    32
#define ECAP    64
#define OVF_CAP 8192

// ---------------- degree histogram over dst ----------------
__global__ __launch_bounds__(256) void hist_kernel(const int* __restrict__ dst,
                                                   int* __restrict__ deg) {
  int e = blockIdx.x * 256 + threadIdx.x;
  if (e < N_EDGES) atomicAdd(&deg[dst[e]], 1);
}

__global__ __launch_bounds__(256) void dinv_kernel(const int* __restrict__ deg,
                                                   float* __restrict__ dinv) {
  int n = blockIdx.x * 256 + threadIdx.x;
  if (n < N_NODES) dinv[n] = rsqrtf((float)deg[n] + 1.0f);
}

// ---------------- bucket scatter: per-dst src list (cap ECAP, overflow list) ----
__global__ __launch_bounds__(256) void scatter_kernel(const int* __restrict__ src,
                                                      const int* __restrict__ dst,
                                                      int* __restrict__ cnt,
                                                      int* __restrict__ elist,
                                                      int* __restrict__ ovf_cnt,
                                                      int* __restrict__ ovf) {
  int e = blockIdx.x * 256 + threadIdx.x;
  if (e >= N_EDGES) return;
  int s = src[e], d = dst[e];
  int pos = atomicAdd(&cnt[d], 1);
  if (pos < ECAP) {
    elist[(size_t)d * ECAP + pos] = s;
  } else {
    int o = atomicAdd(ovf_cnt, 1);
    if (o < OVF_CAP) { ovf[2 * o] = s; ovf[2 * o + 1] = d; }
  }
}

// ---------------- C[N,128] = (relu?)A[N,128] @ W[128,128] ----------------
// W staged in LDS (64KB -> 2 blocks/CU). 32 nodes/block, thread = 4 nodes x 4 feats.
__global__ __launch_bounds__(256) void gemm_kernel(const float* __restrict__ A,
                                                   const float* __restrict__ W,
                                                   float* __restrict__ C,
                                                   int relu_in) {
  __shared__ float sW[NFEAT * NFEAT];
  int tid = threadIdx.x;
  const float4* W4 = (const float4*)W;
  float4* sW4 = (float4*)sW;
  #pragma unroll
  for (int i = 0; i < (NFEAT * NFEAT / 4) / 256; ++i)
    sW4[tid + i * 256] = W4[tid + i * 256];
  __syncthreads();

  int n0 = blockIdx.x * 32;
  int f0 = (tid & 31) * 4;   // output feature group
  int nl = (tid >> 5) * 4;   // local node group

  float acc[4][4] = {};
  #pragma unroll 2
  for (int k = 0; k < NFEAT; k += 4) {
    float a[4][4], w[4][4];
    #pragma unroll
    for (int i = 0; i < 4; ++i) {
      float4 v = *(const float4*)(A + (size_t)(n0 + nl + i) * NFEAT + k);
      if (relu_in) {
        v.x = fmaxf(v.x, 0.f); v.y = fmaxf(v.y, 0.f);
        v.z = fmaxf(v.z, 0.f); v.w = fmaxf(v.w, 0.f);
      }
      a[i][0] = v.x; a[i][1] = v.y; a[i][2] = v.z; a[i][3] = v.w;
    }
    #pragma unroll
    for (int j = 0; j < 4; ++j) {
      float4 v = *(const float4*)&sW[(k + j) * NFEAT + f0];
      w[j][0] = v.x; w[j][1] = v.y; w[j][2] = v.z; w[j][3] = v.w;
    }
    #pragma unroll
    for (int i = 0; i < 4; ++i)
      #pragma unroll
      for (int j = 0; j < 4; ++j)
        #pragma unroll
        for (int c = 0; c < 4; ++c)
          acc[i][c] = fmaf(a[i][j], w[j][c], acc[i][c]);
  }
  #pragma unroll
  for (int i = 0; i < 4; ++i) {
    float4 r; r.x = acc[i][0]; r.y = acc[i][1]; r.z = acc[i][2]; r.w = acc[i][3];
    *(float4*)(C + (size_t)(n0 + nl + i) * NFEAT + f0) = r;
  }
}

// ---------------- gather-based aggregation: one wave per dst node ----------------
// out[n] = sum_{s in adj(n)} dinv[s]*dinv[n]*h[s] + dinv[n]^2*h[n] + bias
__global__ __launch_bounds__(256) void agg_kernel(const float* __restrict__ h,
                                                  const int* __restrict__ elist,
                                                  const int* __restrict__ cnt,
                                                  const float* __restrict__ dinv,
                                                  const float* __restrict__ bias,
                                                  float* __restrict__ out) {
  int n = (blockIdx.x * 256 + threadIdx.x) >> 6;
  int lane = threadIdx.x & 63;
  if (n >= N_NODES) return;
  float dn = dinv[n];
  int c = cnt[n]; c = (c > ECAP) ? ECAP : c;
  const int* el = elist + (size_t)n * ECAP;
  const float2* h2 = (const float2*)h;
  float2 hv = h2[(size_t)n * 64 + lane];
  float sw = dn * dn;
  float ax = sw * hv.x, ay = sw * hv.y;
  for (int j = 0; j < c; ++j) {
    int s = el[j];                 // wave-uniform broadcast load
    float wgt = dinv[s] * dn;
    float2 v = h2[(size_t)s * 64 + lane];  // coalesced 512B gather
    ax = fmaf(wgt, v.x, ax);
    ay = fmaf(wgt, v.y, ay);
  }
  float2 b = ((const float2*)bias)[lane];
  float2 r; r.x = ax + b.x; r.y = ay + b.y;
  ((float2*)out)[(size_t)n * 64 + lane] = r;
}

// ---------------- overflow edges (expected count: 0) ----------------
__global__ __launch_bounds__(128) void ovf_kernel(const float* __restrict__ h,
                                                  const int* __restrict__ ovf,
                                                  const int* __restrict__ ovf_cnt,
                                                  const float* __restrict__ dinv,
                                                  float* __restrict__ out) {
  int m = *ovf_cnt; if (m > OVF_CAP) m = OVF_CAP;
  for (int p = blockIdx.x; p < m; p += gridDim.x) {
    int s = ovf[2 * p], d = ovf[2 * p + 1];
    float w = dinv[s] * dinv[d];
    for (int f = threadIdx.x; f < NFEAT; f += blockDim.x)
      atomicAdd(&out[(size_t)d * NFEAT + f], w * h[(size_t)s * NFEAT + f]);
  }
}

// ---------------- per-graph node counts via binary search (batch sorted) --------
__global__ __launch_bounds__(256) void gcnt_kernel(const int* __restrict__ batch,
                                                   float* __restrict__ invcnt) {
  int g = blockIdx.x * 256 + threadIdx.x;
  if (g >= NGRAPH) return;
  int lo = 0, hi = N_NODES;
  while (lo < hi) { int mid = (lo + hi) >> 1; if (batch[mid] < g) lo = mid + 1; else hi = mid; }
  int lo2 = lo, hi2 = N_NODES;
  while (lo2 < hi2) { int mid = (lo2 + hi2) >> 1; if (batch[mid] < g + 1) lo2 = mid + 1; else hi2 = mid; }
  int c = lo2 - lo;
  invcnt[g] = 1.0f / fmaxf((float)c, 1.0f);
}

// ---------------- pooled sum of relu(h) by (sorted) batch ----------------
#define PCHUNK 256
__global__ __launch_bounds__(64) void pool_kernel(const float* __restrict__ h,
                                                  const int* __restrict__ batch,
                                                  float* __restrict__ gsum) {
  int lane = threadIdx.x;
  int n0 = blockIdx.x * PCHUNK;
  if (n0 >= N_NODES) return;
  int n1 = n0 + PCHUNK; if (n1 > N_NODES) n1 = N_NODES;
  const float2* h2 = (const float2*)h;
  float ax = 0.f, ay = 0.f;
  int cur = batch[n0];
  for (int n = n0; n < n1; ++n) {
    int b = batch[n];                 // wave-uniform
    if (b != cur) {
      atomicAdd(&gsum[cur * NFEAT + 2 * lane], ax);
      atomicAdd(&gsum[cur * NFEAT + 2 * lane + 1], ay);
      ax = 0.f; ay = 0.f; cur = b;
    }
    float2 v = h2[(size_t)n * 64 + lane];
    ax += fmaxf(v.x, 0.f);
    ay += fmaxf(v.y, 0.f);
  }
  atomicAdd(&gsum[cur * NFEAT + 2 * lane], ax);
  atomicAdd(&gsum[cur * NFEAT + 2 * lane + 1], ay);
}

// ---------------- MLP head: out = relu(g@Wl1+bl1)@Wl2+bl2, g = gsum*invcnt ------
__global__ __launch_bounds__(128) void mlp_kernel(const float* __restrict__ gsum,
                                                  const float* __restrict__ invcnt,
                                                  const float* __restrict__ Wl1,
                                                  const float* __restrict__ bl1,
                                                  const float* __restrict__ Wl2,
                                                  const float* __restrict__ bl2,
                                                  float* __restrict__ out) {
  __shared__ float gr[NFEAT];
  __shared__ float t1[NFEAT];
  int g = blockIdx.x, t = threadIdx.x;
  gr[t] = gsum[g * NFEAT + t] * invcnt[g];
  __syncthreads();
  float acc = bl1[t];
  for (int k = 0; k < NFEAT; ++k) acc = fmaf(gr[k], Wl1[k * NFEAT + t], acc);
  t1[t] = fmaxf(acc, 0.f);
  __syncthreads();
  if (t < NACT) {
    float a2 = bl2[t];
    for (int k = 0; k < NFEAT; ++k) a2 = fmaf(t1[k], Wl2[k * NACT + t], a2);
    out[g * NACT + t] = a2;
  }
}

extern "C" void kernel_launch(void* const* d_in, const int* in_sizes, int n_in,
                              void* d_out, int out_size, void* d_ws, size_t ws_size,
                              hipStream_t stream) {
  const float* x    = (const float*)d_in[0];
  const int*   ei   = (const int*)d_in[1];
  const int*   batch= (const int*)d_in[2];
  const float* W1   = (const float*)d_in[3];
  const float* b1   = (const float*)d_in[4];
  const float* W2   = (const float*)d_in[5];
  const float* b2   = (const float*)d_in[6];
  const float* Wl1  = (const float*)d_in[7];
  const float* bl1  = (const float*)d_in[8];
  const float* Wl2  = (const float*)d_in[9];
  const float* bl2  = (const float*)d_in[10];
  float* out = (float*)d_out;

  const int* srcp = ei;            // edge_index[0]
  const int* dstp = ei + N_EDGES;  // edge_index[1]

  // workspace bump allocator (512B aligned); zero-region first. ~130 MB total.
  char* base = (char*)d_ws;
  size_t off = 0;
  auto alloc = [&](size_t bytes) -> void* {
    void* p = base + off;
    off += (bytes + 511) & ~(size_t)511;
    return p;
  };
  int*   deg    = (int*)alloc((size_t)N_NODES * 4);
  int*   cnt    = (int*)alloc((size_t)N_NODES * 4);
  int*   ovfc   = (int*)alloc(4);
  float* gsum   = (float*)alloc((size_t)NGRAPH * NFEAT * 4);
  size_t zspan  = off;  // everything above must start zeroed
  float* dinv   = (float*)alloc((size_t)N_NODES * 4);
  float* invcnt = (float*)alloc((size_t)NGRAPH * 4);
  int*   elist  = (int*)alloc((size_t)N_NODES * ECAP * 4);
  int*   ovf    = (int*)alloc((size_t)OVF_CAP * 2 * 4);
  float* A      = (float*)alloc((size_t)N_NODES * NFEAT * 4);
  float* B      = (float*)alloc((size_t)N_NODES * NFEAT * 4);

  hipMemsetAsync(d_ws, 0, zspan, stream);

  const int EB = (N_EDGES + 255) / 256;   // 6250
  const int NB = (N_NODES + 255) / 256;   // 391

  hist_kernel<<<EB, 256, 0, stream>>>(dstp, deg);
  dinv_kernel<<<NB, 256, 0, stream>>>(deg, dinv);
  scatter_kernel<<<EB, 256, 0, stream>>>(srcp, dstp, cnt, elist, ovfc, ovf);

  // layer 1: A = x @ W1 ; B = agg(A) + selfloop + b1   (relu deferred to gemm2 load)
  gemm_kernel<<<N_NODES / 32, 256, 0, stream>>>(x, W1, A, 0);
  agg_kernel<<<N_NODES / 4, 256, 0, stream>>>(A, elist, cnt, dinv, b1, B);
  ovf_kernel<<<64, 128, 0, stream>>>(A, ovf, ovfc, dinv, B);

  // layer 2: A = relu(B) @ W2 ; B = agg(A) + selfloop + b2 (relu deferred to pool)
  gemm_kernel<<<N_NODES / 32, 256, 0, stream>>>(B, W2, A, 1);
  agg_kernel<<<N_NODES / 4, 256, 0, stream>>>(A, elist, cnt, dinv, b2, B);
  ovf_kernel<<<64, 128, 0, stream>>>(A, ovf, ovfc, dinv, B);

  // pool + head
  gcnt_kernel<<<1, 256, 0, stream>>>(batch, invcnt);
  pool_kernel<<<(N_NODES + PCHUNK - 1) / PCHUNK, 64, 0, stream>>>(B, batch, gsum);
  mlp_kernel<<<NGRAPH, 128, 0, stream>>>(gsum, invcnt, Wl1, bl1, Wl2, bl2, out);
}

// Round 2
// 865.951 us; speedup vs baseline: 1.2056x; 1.2056x over previous
//
#include <hip/hip_runtime.h>
#include <hip/hip_bf16.h>

#define N_NODES 100000
#define N_EDGES 1600000
#define NFEAT   128
#define NGRAPH  256
#define NACT    32
#define ECAP    64
#define OVF_CAP 8192

__device__ inline unsigned short f2bf(float f) {
  __hip_bfloat16 b = __float2bfloat16(f);
  return *reinterpret_cast<unsigned short*>(&b);
}

// ---------------- dinv from bucket counts (cnt == dst-degree) ----------------
__global__ __launch_bounds__(256) void dinv_kernel(const int* __restrict__ cnt,
                                                   float* __restrict__ dinv) {
  int n = blockIdx.x * 256 + threadIdx.x;
  if (n < N_NODES) dinv[n] = rsqrtf((float)cnt[n] + 1.0f);
}

// ---------------- bucket scatter: per-dst src list (cap ECAP, overflow list) ----
__global__ __launch_bounds__(256) void scatter_kernel(const int* __restrict__ src,
                                                      const int* __restrict__ dst,
                                                      int* __restrict__ cnt,
                                                      int* __restrict__ elist,
                                                      int* __restrict__ ovf_cnt,
                                                      int* __restrict__ ovf) {
  int e = blockIdx.x * 256 + threadIdx.x;
  if (e >= N_EDGES) return;
  int s = src[e], d = dst[e];
  int pos = atomicAdd(&cnt[d], 1);
  if (pos < ECAP) {
    elist[(size_t)d * ECAP + pos] = s;
  } else {
    int o = atomicAdd(ovf_cnt, 1);
    if (o < OVF_CAP) { ovf[2 * o] = s; ovf[2 * o + 1] = d; }
  }
}

// ---------------- C[N,128](bf16) = (relu?)A[N,128](f32) @ W[128,128](f32) -------
// W staged in LDS (64KB -> 2 blocks/CU). 32 nodes/block, thread = 4 nodes x 4 feats.
__global__ __launch_bounds__(256) void gemm_kernel(const float* __restrict__ A,
                                                   const float* __restrict__ W,
                                                   unsigned short* __restrict__ C,
                                                   int relu_in) {
  __shared__ float sW[NFEAT * NFEAT];
  int tid = threadIdx.x;
  const float4* W4 = (const float4*)W;
  float4* sW4 = (float4*)sW;
  #pragma unroll
  for (int i = 0; i < (NFEAT * NFEAT / 4) / 256; ++i)
    sW4[tid + i * 256] = W4[tid + i * 256];
  __syncthreads();

  int n0 = blockIdx.x * 32;
  int f0 = (tid & 31) * 4;   // output feature group
  int nl = (tid >> 5) * 4;   // local node group

  float acc[4][4] = {};
  #pragma unroll 2
  for (int k = 0; k < NFEAT; k += 4) {
    float a[4][4], w[4][4];
    #pragma unroll
    for (int i = 0; i < 4; ++i) {
      float4 v = *(const float4*)(A + (size_t)(n0 + nl + i) * NFEAT + k);
      if (relu_in) {
        v.x = fmaxf(v.x, 0.f); v.y = fmaxf(v.y, 0.f);
        v.z = fmaxf(v.z, 0.f); v.w = fmaxf(v.w, 0.f);
      }
      a[i][0] = v.x; a[i][1] = v.y; a[i][2] = v.z; a[i][3] = v.w;
    }
    #pragma unroll
    for (int j = 0; j < 4; ++j) {
      float4 v = *(const float4*)&sW[(k + j) * NFEAT + f0];
      w[j][0] = v.x; w[j][1] = v.y; w[j][2] = v.z; w[j][3] = v.w;
    }
    #pragma unroll
    for (int i = 0; i < 4; ++i)
      #pragma unroll
      for (int j = 0; j < 4; ++j)
        #pragma unroll
        for (int c = 0; c < 4; ++c)
          acc[i][c] = fmaf(a[i][j], w[j][c], acc[i][c]);
  }
  #pragma unroll
  for (int i = 0; i < 4; ++i) {
    ushort4 r;
    r.x = f2bf(acc[i][0]); r.y = f2bf(acc[i][1]);
    r.z = f2bf(acc[i][2]); r.w = f2bf(acc[i][3]);
    *(ushort4*)(C + (size_t)(n0 + nl + i) * NFEAT + f0) = r;
  }
}

// ---------------- gather-based aggregation: one wave per dst node ----------------
// out[n] = sum_{s in adj(n)} dinv[s]*dinv[n]*h[s] + dinv[n]^2*h[n] + bias
// h is bf16 (half the gather bytes); accumulate fp32; out fp32.
__global__ __launch_bounds__(256) void agg_kernel(const __hip_bfloat162* __restrict__ h2,
                                                  const int* __restrict__ elist,
                                                  const int* __restrict__ cnt,
                                                  const float* __restrict__ dinv,
                                                  const float* __restrict__ bias,
                                                  float* __restrict__ out) {
  int n = (blockIdx.x * 256 + threadIdx.x) >> 6;
  int lane = threadIdx.x & 63;
  if (n >= N_NODES) return;
  float dn = dinv[n];
  int c = cnt[n]; c = (c > ECAP) ? ECAP : c;
  const int* el = elist + (size_t)n * ECAP;
  float2 hv = __bfloat1622float2(h2[(size_t)n * 64 + lane]);
  float sw = dn * dn;
  float ax = sw * hv.x, ay = sw * hv.y;
  for (int j = 0; j < c; ++j) {
    int s = el[j];                 // wave-uniform broadcast load
    float wgt = dinv[s] * dn;
    float2 v = __bfloat1622float2(h2[(size_t)s * 64 + lane]);  // 256B/wave gather
    ax = fmaf(wgt, v.x, ax);
    ay = fmaf(wgt, v.y, ay);
  }
  float2 b = ((const float2*)bias)[lane];
  float2 r; r.x = ax + b.x; r.y = ay + b.y;
  ((float2*)out)[(size_t)n * 64 + lane] = r;
}

// ---------------- overflow edges (expected count: 0) ----------------
__global__ __launch_bounds__(128) void ovf_kernel(const __hip_bfloat16* __restrict__ h,
                                                  const int* __restrict__ ovf,
                                                  const int* __restrict__ ovf_cnt,
                                                  const float* __restrict__ dinv,
                                                  float* __restrict__ out) {
  int m = *ovf_cnt; if (m > OVF_CAP) m = OVF_CAP;
  for (int p = blockIdx.x; p < m; p += gridDim.x) {
    int s = ovf[2 * p], d = ovf[2 * p + 1];
    float w = dinv[s] * dinv[d];
    for (int f = threadIdx.x; f < NFEAT; f += blockDim.x)
      atomicAdd(&out[(size_t)d * NFEAT + f],
                w * __bfloat162float(h[(size_t)s * NFEAT + f]));
  }
}

// ---------------- per-graph node counts via binary search (batch sorted) --------
__global__ __launch_bounds__(256) void gcnt_kernel(const int* __restrict__ batch,
                                                   float* __restrict__ invcnt) {
  int g = blockIdx.x * 256 + threadIdx.x;
  if (g >= NGRAPH) return;
  int lo = 0, hi = N_NODES;
  while (lo < hi) { int mid = (lo + hi) >> 1; if (batch[mid] < g) lo = mid + 1; else hi = mid; }
  int lo2 = lo, hi2 = N_NODES;
  while (lo2 < hi2) { int mid = (lo2 + hi2) >> 1; if (batch[mid] < g + 1) lo2 = mid + 1; else hi2 = mid; }
  int c = lo2 - lo;
  invcnt[g] = 1.0f / fmaxf((float)c, 1.0f);
}

// ---------------- pooled sum of relu(h) by (sorted) batch ----------------
#define PCHUNK 64
__global__ __launch_bounds__(64) void pool_kernel(const float* __restrict__ h,
                                                  const int* __restrict__ batch,
                                                  float* __restrict__ gsum) {
  int lane = threadIdx.x;
  int n0 = blockIdx.x * PCHUNK;
  if (n0 >= N_NODES) return;
  int n1 = n0 + PCHUNK; if (n1 > N_NODES) n1 = N_NODES;
  const float2* h2 = (const float2*)h;
  float ax = 0.f, ay = 0.f;
  int cur = batch[n0];
  for (int n = n0; n < n1; ++n) {
    int b = batch[n];                 // wave-uniform
    if (b != cur) {
      atomicAdd(&gsum[cur * NFEAT + 2 * lane], ax);
      atomicAdd(&gsum[cur * NFEAT + 2 * lane + 1], ay);
      ax = 0.f; ay = 0.f; cur = b;
    }
    float2 v = h2[(size_t)n * 64 + lane];
    ax += fmaxf(v.x, 0.f);
    ay += fmaxf(v.y, 0.f);
  }
  atomicAdd(&gsum[cur * NFEAT + 2 * lane], ax);
  atomicAdd(&gsum[cur * NFEAT + 2 * lane + 1], ay);
}

// ---------------- MLP head: out = relu(g@Wl1+bl1)@Wl2+bl2, g = gsum*invcnt ------
__global__ __launch_bounds__(128) void mlp_kernel(const float* __restrict__ gsum,
                                                  const float* __restrict__ invcnt,
                                                  const float* __restrict__ Wl1,
                                                  const float* __restrict__ bl1,
                                                  const float* __restrict__ Wl2,
                                                  const float* __restrict__ bl2,
                                                  float* __restrict__ out) {
  __shared__ float gr[NFEAT];
  __shared__ float t1[NFEAT];
  int g = blockIdx.x, t = threadIdx.x;
  gr[t] = gsum[g * NFEAT + t] * invcnt[g];
  __syncthreads();
  float acc = bl1[t];
  for (int k = 0; k < NFEAT; ++k) acc = fmaf(gr[k], Wl1[k * NFEAT + t], acc);
  t1[t] = fmaxf(acc, 0.f);
  __syncthreads();
  if (t < NACT) {
    float a2 = bl2[t];
    for (int k = 0; k < NFEAT; ++k) a2 = fmaf(t1[k], Wl2[k * NACT + t], a2);
    out[g * NACT + t] = a2;
  }
}

extern "C" void kernel_launch(void* const* d_in, const int* in_sizes, int n_in,
                              void* d_out, int out_size, void* d_ws, size_t ws_size,
                              hipStream_t stream) {
  const float* x    = (const float*)d_in[0];
  const int*   ei   = (const int*)d_in[1];
  const int*   batch= (const int*)d_in[2];
  const float* W1   = (const float*)d_in[3];
  const float* b1   = (const float*)d_in[4];
  const float* W2   = (const float*)d_in[5];
  const float* b2   = (const float*)d_in[6];
  const float* Wl1  = (const float*)d_in[7];
  const float* bl1  = (const float*)d_in[8];
  const float* Wl2  = (const float*)d_in[9];
  const float* bl2  = (const float*)d_in[10];
  float* out = (float*)d_out;

  const int* srcp = ei;            // edge_index[0]
  const int* dstp = ei + N_EDGES;  // edge_index[1]

  // workspace bump allocator (512B aligned); zero-region first.
  char* base = (char*)d_ws;
  size_t off = 0;
  auto alloc = [&](size_t bytes) -> void* {
    void* p = base + off;
    off += (bytes + 511) & ~(size_t)511;
    return p;
  };
  int*   cnt    = (int*)alloc((size_t)N_NODES * 4);
  int*   ovfc   = (int*)alloc(4);
  float* gsum   = (float*)alloc((size_t)NGRAPH * NFEAT * 4);
  size_t zspan  = off;  // everything above must start zeroed
  float* dinv   = (float*)alloc((size_t)N_NODES * 4);
  float* invcnt = (float*)alloc((size_t)NGRAPH * 4);
  int*   elist  = (int*)alloc((size_t)N_NODES * ECAP * 4);
  int*   ovf    = (int*)alloc((size_t)OVF_CAP * 2 * 4);
  unsigned short* A = (unsigned short*)alloc((size_t)N_NODES * NFEAT * 2); // bf16 h
  float* B      = (float*)alloc((size_t)N_NODES * NFEAT * 4);              // agg out

  hipMemsetAsync(d_ws, 0, zspan, stream);

  const int EB = (N_EDGES + 255) / 256;   // 6250
  const int NB = (N_NODES + 255) / 256;   // 391

  scatter_kernel<<<EB, 256, 0, stream>>>(srcp, dstp, cnt, elist, ovfc, ovf);
  dinv_kernel<<<NB, 256, 0, stream>>>(cnt, dinv);

  // layer 1: A(bf16) = x @ W1 ; B = agg(A) + selfloop + b1 (relu deferred to gemm2)
  gemm_kernel<<<N_NODES / 32, 256, 0, stream>>>(x, W1, A, 0);
  agg_kernel<<<N_NODES / 4, 256, 0, stream>>>((const __hip_bfloat162*)A, elist, cnt, dinv, b1, B);
  ovf_kernel<<<64, 128, 0, stream>>>((const __hip_bfloat16*)A, ovf, ovfc, dinv, B);

  // layer 2: A(bf16) = relu(B) @ W2 ; B = agg(A) + selfloop + b2 (relu at pool)
  gemm_kernel<<<N_NODES / 32, 256, 0, stream>>>(B, W2, A, 1);
  agg_kernel<<<N_NODES / 4, 256, 0, stream>>>((const __hip_bfloat162*)A, elist, cnt, dinv, b2, B);
  ovf_kernel<<<64, 128, 0, stream>>>((const __hip_bfloat16*)A, ovf, ovfc, dinv, B);

  // pool + head
  gcnt_kernel<<<1, 256, 0, stream>>>(batch, invcnt);
  pool_kernel<<<(N_NODES + PCHUNK - 1) / PCHUNK, 64, 0, stream>>>(B, batch, gsum);
  mlp_kernel<<<NGRAPH, 128, 0, stream>>>(gsum, invcnt, Wl1, bl1, Wl2, bl2, out);
}

// Round 3
// 693.769 us; speedup vs baseline: 1.5048x; 1.2482x over previous
//
#include <hip/hip_runtime.h>
#include <hip/hip_bf16.h>

#define N_NODES 100000
#define N_EDGES 1600000
#define NFEAT   128
#define NGRAPH  256
#define NACT    32
#define ECAP    64
#define OVF_CAP 8192

__device__ inline unsigned short f2bf(float f) {
  __hip_bfloat16 b = __float2bfloat16(f);
  return *reinterpret_cast<unsigned short*>(&b);
}

// ---------------- dinv from bucket counts (cnt == dst-degree) ----------------
__global__ __launch_bounds__(256) void dinv_kernel(const int* __restrict__ cnt,
                                                   float* __restrict__ dinv) {
  int n = blockIdx.x * 256 + threadIdx.x;
  if (n < N_NODES) dinv[n] = rsqrtf((float)cnt[n] + 1.0f);
}

// ---------------- bucket scatter: per-dst src list (cap ECAP, overflow list) ----
__global__ __launch_bounds__(256) void scatter_kernel(const int* __restrict__ src,
                                                      const int* __restrict__ dst,
                                                      int* __restrict__ cnt,
                                                      int* __restrict__ elist,
                                                      int* __restrict__ ovf_cnt,
                                                      int* __restrict__ ovf) {
  int e = blockIdx.x * 256 + threadIdx.x;
  if (e >= N_EDGES) return;
  int s = src[e], d = dst[e];
  int pos = atomicAdd(&cnt[d], 1);
  if (pos < ECAP) {
    elist[(size_t)d * ECAP + pos] = s;
  } else {
    int o = atomicAdd(ovf_cnt, 1);
    if (o < OVF_CAP) { ovf[2 * o] = s; ovf[2 * o + 1] = d; }
  }
}

// ---------------- C[N,128](bf16) = (relu?)A[N,128](f32) @ W[128,128](f32) -------
// W staged in LDS (64KB -> 2 blocks/CU). 32 nodes/block, thread = 4 nodes x 4 feats.
__global__ __launch_bounds__(256) void gemm_kernel(const float* __restrict__ A,
                                                   const float* __restrict__ W,
                                                   unsigned short* __restrict__ C,
                                                   int relu_in) {
  __shared__ float sW[NFEAT * NFEAT];
  int tid = threadIdx.x;
  const float4* W4 = (const float4*)W;
  float4* sW4 = (float4*)sW;
  #pragma unroll
  for (int i = 0; i < (NFEAT * NFEAT / 4) / 256; ++i)
    sW4[tid + i * 256] = W4[tid + i * 256];
  __syncthreads();

  int n0 = blockIdx.x * 32;
  int f0 = (tid & 31) * 4;   // output feature group
  int nl = (tid >> 5) * 4;   // local node group

  float acc[4][4] = {};
  #pragma unroll 2
  for (int k = 0; k < NFEAT; k += 4) {
    float a[4][4], w[4][4];
    #pragma unroll
    for (int i = 0; i < 4; ++i) {
      float4 v = *(const float4*)(A + (size_t)(n0 + nl + i) * NFEAT + k);
      if (relu_in) {
        v.x = fmaxf(v.x, 0.f); v.y = fmaxf(v.y, 0.f);
        v.z = fmaxf(v.z, 0.f); v.w = fmaxf(v.w, 0.f);
      }
      a[i][0] = v.x; a[i][1] = v.y; a[i][2] = v.z; a[i][3] = v.w;
    }
    #pragma unroll
    for (int j = 0; j < 4; ++j) {
      float4 v = *(const float4*)&sW[(k + j) * NFEAT + f0];
      w[j][0] = v.x; w[j][1] = v.y; w[j][2] = v.z; w[j][3] = v.w;
    }
    #pragma unroll
    for (int i = 0; i < 4; ++i)
      #pragma unroll
      for (int j = 0; j < 4; ++j)
        #pragma unroll
        for (int c = 0; c < 4; ++c)
          acc[i][c] = fmaf(a[i][j], w[j][c], acc[i][c]);
  }
  #pragma unroll
  for (int i = 0; i < 4; ++i) {
    ushort4 r;
    r.x = f2bf(acc[i][0]); r.y = f2bf(acc[i][1]);
    r.z = f2bf(acc[i][2]); r.w = f2bf(acc[i][3]);
    *(ushort4*)(C + (size_t)(n0 + nl + i) * NFEAT + f0) = r;
  }
}

// ---------------- gather-based aggregation: one wave per dst node ----------------
// out[n] = sum_{s in adj(n)} dinv[s]*dinv[n]*h[s] + dinv[n]^2*h[n] + bias
// h is bf16; edge list + weights prefetched lane-parallel, broadcast via shfl,
// inner loop unrolled x4 so 4 independent 256B gathers are in flight per wave.
__global__ __launch_bounds__(256) void agg_kernel(const __hip_bfloat162* __restrict__ h2,
                                                  const int* __restrict__ elist,
                                                  const int* __restrict__ cnt,
                                                  const float* __restrict__ dinv,
                                                  const float* __restrict__ bias,
                                                  float* __restrict__ out) {
  int n = (blockIdx.x * 256 + threadIdx.x) >> 6;
  int lane = threadIdx.x & 63;
  if (n >= N_NODES) return;
  float dn = dinv[n];
  int c = cnt[n]; c = (c > ECAP) ? ECAP : c;
  const int* el = elist + (size_t)n * ECAP;

  // lane-parallel prefetch: one coalesced 256B load of el + one 4B dinv gather
  int   s_l = (lane < c) ? el[lane] : 0;
  float w_l = (lane < c) ? dinv[s_l] * dn : 0.f;

  float2 hv = __bfloat1622float2(h2[(size_t)n * 64 + lane]);
  float sw = dn * dn;
  float ax = sw * hv.x, ay = sw * hv.y;

  int j = 0;
  for (; j + 4 <= c; j += 4) {
    int   s0 = __shfl(s_l, j),     s1 = __shfl(s_l, j + 1);
    int   s2 = __shfl(s_l, j + 2), s3 = __shfl(s_l, j + 3);
    float w0 = __shfl(w_l, j),     w1 = __shfl(w_l, j + 1);
    float w2 = __shfl(w_l, j + 2), w3 = __shfl(w_l, j + 3);
    float2 v0 = __bfloat1622float2(h2[(size_t)s0 * 64 + lane]);
    float2 v1 = __bfloat1622float2(h2[(size_t)s1 * 64 + lane]);
    float2 v2 = __bfloat1622float2(h2[(size_t)s2 * 64 + lane]);
    float2 v3 = __bfloat1622float2(h2[(size_t)s3 * 64 + lane]);
    ax = fmaf(w0, v0.x, ax); ay = fmaf(w0, v0.y, ay);
    ax = fmaf(w1, v1.x, ax); ay = fmaf(w1, v1.y, ay);
    ax = fmaf(w2, v2.x, ax); ay = fmaf(w2, v2.y, ay);
    ax = fmaf(w3, v3.x, ax); ay = fmaf(w3, v3.y, ay);
  }
  for (; j < c; ++j) {
    int   s = __shfl(s_l, j);
    float w = __shfl(w_l, j);
    float2 v = __bfloat1622float2(h2[(size_t)s * 64 + lane]);
    ax = fmaf(w, v.x, ax); ay = fmaf(w, v.y, ay);
  }
  float2 b = ((const float2*)bias)[lane];
  float2 r; r.x = ax + b.x; r.y = ay + b.y;
  ((float2*)out)[(size_t)n * 64 + lane] = r;
}

// ---------------- overflow edges (expected count: 0) ----------------
__global__ __launch_bounds__(128) void ovf_kernel(const __hip_bfloat16* __restrict__ h,
                                                  const int* __restrict__ ovf,
                                                  const int* __restrict__ ovf_cnt,
                                                  const float* __restrict__ dinv,
                                                  float* __restrict__ out) {
  int m = *ovf_cnt; if (m > OVF_CAP) m = OVF_CAP;
  for (int p = blockIdx.x; p < m; p += gridDim.x) {
    int s = ovf[2 * p], d = ovf[2 * p + 1];
    float w = dinv[s] * dinv[d];
    for (int f = threadIdx.x; f < NFEAT; f += blockDim.x)
      atomicAdd(&out[(size_t)d * NFEAT + f],
                w * __bfloat162float(h[(size_t)s * NFEAT + f]));
  }
}

// ---------------- per-graph node counts via binary search (batch sorted) --------
__global__ __launch_bounds__(256) void gcnt_kernel(const int* __restrict__ batch,
                                                   float* __restrict__ invcnt) {
  int g = blockIdx.x * 256 + threadIdx.x;
  if (g >= NGRAPH) return;
  int lo = 0, hi = N_NODES;
  while (lo < hi) { int mid = (lo + hi) >> 1; if (batch[mid] < g) lo = mid + 1; else hi = mid; }
  int lo2 = lo, hi2 = N_NODES;
  while (lo2 < hi2) { int mid = (lo2 + hi2) >> 1; if (batch[mid] < g + 1) lo2 = mid + 1; else hi2 = mid; }
  int c = lo2 - lo;
  invcnt[g] = 1.0f / fmaxf((float)c, 1.0f);
}

// ---------------- pooled sum of relu(h) by (sorted) batch ----------------
#define PCHUNK 64
__global__ __launch_bounds__(64) void pool_kernel(const float* __restrict__ h,
                                                  const int* __restrict__ batch,
                                                  float* __restrict__ gsum) {
  int lane = threadIdx.x;
  int n0 = blockIdx.x * PCHUNK;
  if (n0 >= N_NODES) return;
  int n1 = n0 + PCHUNK; if (n1 > N_NODES) n1 = N_NODES;
  const float2* h2 = (const float2*)h;
  float ax = 0.f, ay = 0.f;
  int cur = batch[n0];
  for (int n = n0; n < n1; ++n) {
    int b = batch[n];                 // wave-uniform
    if (b != cur) {
      atomicAdd(&gsum[cur * NFEAT + 2 * lane], ax);
      atomicAdd(&gsum[cur * NFEAT + 2 * lane + 1], ay);
      ax = 0.f; ay = 0.f; cur = b;
    }
    float2 v = h2[(size_t)n * 64 + lane];
    ax += fmaxf(v.x, 0.f);
    ay += fmaxf(v.y, 0.f);
  }
  atomicAdd(&gsum[cur * NFEAT + 2 * lane], ax);
  atomicAdd(&gsum[cur * NFEAT + 2 * lane + 1], ay);
}

// ---------------- MLP head: out = relu(g@Wl1+bl1)@Wl2+bl2, g = gsum*invcnt ------
__global__ __launch_bounds__(128) void mlp_kernel(const float* __restrict__ gsum,
                                                  const float* __restrict__ invcnt,
                                                  const float* __restrict__ Wl1,
                                                  const float* __restrict__ bl1,
                                                  const float* __restrict__ Wl2,
                                                  const float* __restrict__ bl2,
                                                  float* __restrict__ out) {
  __shared__ float gr[NFEAT];
  __shared__ float t1[NFEAT];
  int g = blockIdx.x, t = threadIdx.x;
  gr[t] = gsum[g * NFEAT + t] * invcnt[g];
  __syncthreads();
  float acc = bl1[t];
  for (int k = 0; k < NFEAT; ++k) acc = fmaf(gr[k], Wl1[k * NFEAT + t], acc);
  t1[t] = fmaxf(acc, 0.f);
  __syncthreads();
  if (t < NACT) {
    float a2 = bl2[t];
    for (int k = 0; k < NFEAT; ++k) a2 = fmaf(t1[k], Wl2[k * NACT + t], a2);
    out[g * NACT + t] = a2;
  }
}

extern "C" void kernel_launch(void* const* d_in, const int* in_sizes, int n_in,
                              void* d_out, int out_size, void* d_ws, size_t ws_size,
                              hipStream_t stream) {
  const float* x    = (const float*)d_in[0];
  const int*   ei   = (const int*)d_in[1];
  const int*   batch= (const int*)d_in[2];
  const float* W1   = (const float*)d_in[3];
  const float* b1   = (const float*)d_in[4];
  const float* W2   = (const float*)d_in[5];
  const float* b2   = (const float*)d_in[6];
  const float* Wl1  = (const float*)d_in[7];
  const float* bl1  = (const float*)d_in[8];
  const float* Wl2  = (const float*)d_in[9];
  const float* bl2  = (const float*)d_in[10];
  float* out = (float*)d_out;

  const int* srcp = ei;            // edge_index[0]
  const int* dstp = ei + N_EDGES;  // edge_index[1]

  // workspace bump allocator (512B aligned); zero-region first.
  char* base = (char*)d_ws;
  size_t off = 0;
  auto alloc = [&](size_t bytes) -> void* {
    void* p = base + off;
    off += (bytes + 511) & ~(size_t)511;
    return p;
  };
  int*   cnt    = (int*)alloc((size_t)N_NODES * 4);
  int*   ovfc   = (int*)alloc(4);
  float* gsum   = (float*)alloc((size_t)NGRAPH * NFEAT * 4);
  size_t zspan  = off;  // everything above must start zeroed
  float* dinv   = (float*)alloc((size_t)N_NODES * 4);
  float* invcnt = (float*)alloc((size_t)NGRAPH * 4);
  int*   elist  = (int*)alloc((size_t)N_NODES * ECAP * 4);
  int*   ovf    = (int*)alloc((size_t)OVF_CAP * 2 * 4);
  unsigned short* A = (unsigned short*)alloc((size_t)N_NODES * NFEAT * 2); // bf16 h
  float* B      = (float*)alloc((size_t)N_NODES * NFEAT * 4);              // agg out

  hipMemsetAsync(d_ws, 0, zspan, stream);

  const int EB = (N_EDGES + 255) / 256;   // 6250
  const int NB = (N_NODES + 255) / 256;   // 391

  scatter_kernel<<<EB, 256, 0, stream>>>(srcp, dstp, cnt, elist, ovfc, ovf);
  dinv_kernel<<<NB, 256, 0, stream>>>(cnt, dinv);

  // layer 1: A(bf16) = x @ W1 ; B = agg(A) + selfloop + b1 (relu deferred to gemm2)
  gemm_kernel<<<N_NODES / 32, 256, 0, stream>>>(x, W1, A, 0);
  agg_kernel<<<N_NODES / 4, 256, 0, stream>>>((const __hip_bfloat162*)A, elist, cnt, dinv, b1, B);
  ovf_kernel<<<64, 128, 0, stream>>>((const __hip_bfloat16*)A, ovf, ovfc, dinv, B);

  // layer 2: A(bf16) = relu(B) @ W2 ; B = agg(A) + selfloop + b2 (relu at pool)
  gemm_kernel<<<N_NODES / 32, 256, 0, stream>>>(B, W2, A, 1);
  agg_kernel<<<N_NODES / 4, 256, 0, stream>>>((const __hip_bfloat162*)A, elist, cnt, dinv, b2, B);
  ovf_kernel<<<64, 128, 0, stream>>>((const __hip_bfloat16*)A, ovf, ovfc, dinv, B);

  // pool + head
  gcnt_kernel<<<1, 256, 0, stream>>>(batch, invcnt);
  pool_kernel<<<(N_NODES + PCHUNK - 1) / PCHUNK, 64, 0, stream>>>(B, batch, gsum);
  mlp_kernel<<<NGRAPH, 128, 0, stream>>>(gsum, invcnt, Wl1, bl1, Wl2, bl2, out);
}

// Round 4
// 495.723 us; speedup vs baseline: 2.1059x; 1.3995x over previous
//
#include <hip/hip_runtime.h>
#include <hip/hip_bf16.h>

#define N_NODES 100000
#define N_EDGES 1600000
#define NFEAT   128
#define NGRAPH  256
#define NACT    32
#define ECAP    64
#define OVF_CAP 8192

typedef __attribute__((ext_vector_type(8))) short bf16x8;
typedef __attribute__((ext_vector_type(4))) float f32x4;

__device__ inline unsigned short f2bf(float f) {
  __hip_bfloat16 b = __float2bfloat16(f);
  return *reinterpret_cast<unsigned short*>(&b);
}

// ---------------- dinv from bucket counts (cnt == dst-degree) ----------------
__global__ __launch_bounds__(256) void dinv_kernel(const int* __restrict__ cnt,
                                                   float* __restrict__ dinv) {
  int n = blockIdx.x * 256 + threadIdx.x;
  if (n < N_NODES) dinv[n] = rsqrtf((float)cnt[n] + 1.0f);
}

// ---------------- bucket scatter: per-dst src list (cap ECAP, overflow list) ----
__global__ __launch_bounds__(256) void scatter_kernel(const int* __restrict__ src,
                                                      const int* __restrict__ dst,
                                                      int* __restrict__ cnt,
                                                      int* __restrict__ elist,
                                                      int* __restrict__ ovf_cnt,
                                                      int* __restrict__ ovf) {
  int e = blockIdx.x * 256 + threadIdx.x;
  if (e >= N_EDGES) return;
  int s = src[e], d = dst[e];
  int pos = atomicAdd(&cnt[d], 1);
  if (pos < ECAP) {
    elist[(size_t)d * ECAP + pos] = s;
  } else {
    int o = atomicAdd(ovf_cnt, 1);
    if (o < OVF_CAP) { ovf[2 * o] = s; ovf[2 * o + 1] = d; }
  }
}

// ---------------- Wt[n][k] = bf16(W[k][n]) — once per call, 16K elems ----------
__global__ __launch_bounds__(256) void wt_kernel(const float* __restrict__ W,
                                                 unsigned short* __restrict__ Wt) {
  int i = blockIdx.x * 256 + threadIdx.x;
  if (i >= NFEAT * NFEAT) return;
  int n = i >> 7, k = i & 127;
  Wt[n * NFEAT + k] = f2bf(W[k * NFEAT + n]);
}

// ---------------- C[N,128](bf16) = (relu?)A[N,128](f32) @ W via MFMA ------------
// No LDS. Wt (32KB bf16, transposed) is L1-resident. 4 waves/block, wave = 16
// nodes x 128 cols. Fragment layouts (verified m89/m91/m120):
//   A: [m=lane&15][k=quad*8+j]   B: [k=quad*8+j][n=lane&15]
//   D: row=quad*4+reg, col=lane&15
__global__ __launch_bounds__(256) void gemm_mfma_kernel(const float* __restrict__ A,
                                                        const unsigned short* __restrict__ Wt,
                                                        unsigned short* __restrict__ C,
                                                        int relu_in) {
  int tid = threadIdx.x;
  int wave = tid >> 6, lane = tid & 63;
  int q = lane >> 4, r = lane & 15;
  int m0 = blockIdx.x * 64 + wave * 16;
  int arow = m0 + r; if (arow > N_NODES - 1) arow = N_NODES - 1;
  const float* Arow = A + (size_t)arow * NFEAT;

  f32x4 acc[8];
  #pragma unroll
  for (int t = 0; t < 8; ++t) acc[t] = (f32x4){0.f, 0.f, 0.f, 0.f};

  #pragma unroll
  for (int s = 0; s < 4; ++s) {
    int k0 = s * 32 + q * 8;
    float4 a0 = *(const float4*)(Arow + k0);
    float4 a1 = *(const float4*)(Arow + k0 + 4);
    if (relu_in) {
      a0.x = fmaxf(a0.x, 0.f); a0.y = fmaxf(a0.y, 0.f);
      a0.z = fmaxf(a0.z, 0.f); a0.w = fmaxf(a0.w, 0.f);
      a1.x = fmaxf(a1.x, 0.f); a1.y = fmaxf(a1.y, 0.f);
      a1.z = fmaxf(a1.z, 0.f); a1.w = fmaxf(a1.w, 0.f);
    }
    bf16x8 af;
    af[0] = (short)f2bf(a0.x); af[1] = (short)f2bf(a0.y);
    af[2] = (short)f2bf(a0.z); af[3] = (short)f2bf(a0.w);
    af[4] = (short)f2bf(a1.x); af[5] = (short)f2bf(a1.y);
    af[6] = (short)f2bf(a1.z); af[7] = (short)f2bf(a1.w);
    #pragma unroll
    for (int t = 0; t < 8; ++t) {
      bf16x8 bf = *(const bf16x8*)(Wt + (size_t)(t * 16 + r) * NFEAT + k0);
      acc[t] = __builtin_amdgcn_mfma_f32_16x16x32_bf16(af, bf, acc[t], 0, 0, 0);
    }
  }

  #pragma unroll
  for (int t = 0; t < 8; ++t) {
    #pragma unroll
    for (int rr = 0; rr < 4; ++rr) {
      int row = m0 + q * 4 + rr;
      if (row < N_NODES)
        C[(size_t)row * NFEAT + t * 16 + r] = f2bf(acc[t][rr]);
    }
  }
}

// ---------------- gather-based aggregation: one wave per dst node ----------------
// out[n] = sum_{s in adj(n)} dinv[s]*dinv[n]*h[s] + dinv[n]^2*h[n] + bias
__global__ __launch_bounds__(256) void agg_kernel(const __hip_bfloat162* __restrict__ h2,
                                                  const int* __restrict__ elist,
                                                  const int* __restrict__ cnt,
                                                  const float* __restrict__ dinv,
                                                  const float* __restrict__ bias,
                                                  float* __restrict__ out) {
  int n = (blockIdx.x * 256 + threadIdx.x) >> 6;
  int lane = threadIdx.x & 63;
  if (n >= N_NODES) return;
  float dn = dinv[n];
  int c = cnt[n]; c = (c > ECAP) ? ECAP : c;
  const int* el = elist + (size_t)n * ECAP;

  int   s_l = (lane < c) ? el[lane] : 0;
  float w_l = (lane < c) ? dinv[s_l] * dn : 0.f;

  float2 hv = __bfloat1622float2(h2[(size_t)n * 64 + lane]);
  float sw = dn * dn;
  float ax = sw * hv.x, ay = sw * hv.y;

  int j = 0;
  for (; j + 4 <= c; j += 4) {
    int   s0 = __shfl(s_l, j),     s1 = __shfl(s_l, j + 1);
    int   s2 = __shfl(s_l, j + 2), s3 = __shfl(s_l, j + 3);
    float w0 = __shfl(w_l, j),     w1 = __shfl(w_l, j + 1);
    float w2 = __shfl(w_l, j + 2), w3 = __shfl(w_l, j + 3);
    float2 v0 = __bfloat1622float2(h2[(size_t)s0 * 64 + lane]);
    float2 v1 = __bfloat1622float2(h2[(size_t)s1 * 64 + lane]);
    float2 v2 = __bfloat1622float2(h2[(size_t)s2 * 64 + lane]);
    float2 v3 = __bfloat1622float2(h2[(size_t)s3 * 64 + lane]);
    ax = fmaf(w0, v0.x, ax); ay = fmaf(w0, v0.y, ay);
    ax = fmaf(w1, v1.x, ax); ay = fmaf(w1, v1.y, ay);
    ax = fmaf(w2, v2.x, ax); ay = fmaf(w2, v2.y, ay);
    ax = fmaf(w3, v3.x, ax); ay = fmaf(w3, v3.y, ay);
  }
  for (; j < c; ++j) {
    int   s = __shfl(s_l, j);
    float w = __shfl(w_l, j);
    float2 v = __bfloat1622float2(h2[(size_t)s * 64 + lane]);
    ax = fmaf(w, v.x, ax); ay = fmaf(w, v.y, ay);
  }
  float2 b = ((const float2*)bias)[lane];
  float2 r; r.x = ax + b.x; r.y = ay + b.y;
  ((float2*)out)[(size_t)n * 64 + lane] = r;
}

// ---------------- overflow edges (expected count: 0) ----------------
__global__ __launch_bounds__(128) void ovf_kernel(const __hip_bfloat16* __restrict__ h,
                                                  const int* __restrict__ ovf,
                                                  const int* __restrict__ ovf_cnt,
                                                  const float* __restrict__ dinv,
                                                  float* __restrict__ out) {
  int m = *ovf_cnt; if (m > OVF_CAP) m = OVF_CAP;
  for (int p = blockIdx.x; p < m; p += gridDim.x) {
    int s = ovf[2 * p], d = ovf[2 * p + 1];
    float w = dinv[s] * dinv[d];
    for (int f = threadIdx.x; f < NFEAT; f += blockDim.x)
      atomicAdd(&out[(size_t)d * NFEAT + f],
                w * __bfloat162float(h[(size_t)s * NFEAT + f]));
  }
}

// ---------------- per-graph node counts via binary search (batch sorted) --------
__global__ __launch_bounds__(256) void gcnt_kernel(const int* __restrict__ batch,
                                                   float* __restrict__ invcnt) {
  int g = blockIdx.x * 256 + threadIdx.x;
  if (g >= NGRAPH) return;
  int lo = 0, hi = N_NODES;
  while (lo < hi) { int mid = (lo + hi) >> 1; if (batch[mid] < g) lo = mid + 1; else hi = mid; }
  int lo2 = lo, hi2 = N_NODES;
  while (lo2 < hi2) { int mid = (lo2 + hi2) >> 1; if (batch[mid] < g + 1) lo2 = mid + 1; else hi2 = mid; }
  int c = lo2 - lo;
  invcnt[g] = 1.0f / fmaxf((float)c, 1.0f);
}

// ---------------- pooled sum of relu(h) by (sorted) batch ----------------
#define PCHUNK 64
__global__ __launch_bounds__(64) void pool_kernel(const float* __restrict__ h,
                                                  const int* __restrict__ batch,
                                                  float* __restrict__ gsum) {
  int lane = threadIdx.x;
  int n0 = blockIdx.x * PCHUNK;
  if (n0 >= N_NODES) return;
  int n1 = n0 + PCHUNK; if (n1 > N_NODES) n1 = N_NODES;
  const float2* h2 = (const float2*)h;
  float ax = 0.f, ay = 0.f;
  int cur = batch[n0];
  for (int n = n0; n < n1; ++n) {
    int b = batch[n];                 // wave-uniform
    if (b != cur) {
      atomicAdd(&gsum[cur * NFEAT + 2 * lane], ax);
      atomicAdd(&gsum[cur * NFEAT + 2 * lane + 1], ay);
      ax = 0.f; ay = 0.f; cur = b;
    }
    float2 v = h2[(size_t)n * 64 + lane];
    ax += fmaxf(v.x, 0.f);
    ay += fmaxf(v.y, 0.f);
  }
  atomicAdd(&gsum[cur * NFEAT + 2 * lane], ax);
  atomicAdd(&gsum[cur * NFEAT + 2 * lane + 1], ay);
}

// ---------------- MLP head: out = relu(g@Wl1+bl1)@Wl2+bl2, g = gsum*invcnt ------
__global__ __launch_bounds__(128) void mlp_kernel(const float* __restrict__ gsum,
                                                  const float* __restrict__ invcnt,
                                                  const float* __restrict__ Wl1,
                                                  const float* __restrict__ bl1,
                                                  const float* __restrict__ Wl2,
                                                  const float* __restrict__ bl2,
                                                  float* __restrict__ out) {
  __shared__ float gr[NFEAT];
  __shared__ float t1[NFEAT];
  int g = blockIdx.x, t = threadIdx.x;
  gr[t] = gsum[g * NFEAT + t] * invcnt[g];
  __syncthreads();
  float acc = bl1[t];
  for (int k = 0; k < NFEAT; ++k) acc = fmaf(gr[k], Wl1[k * NFEAT + t], acc);
  t1[t] = fmaxf(acc, 0.f);
  __syncthreads();
  if (t < NACT) {
    float a2 = bl2[t];
    for (int k = 0; k < NFEAT; ++k) a2 = fmaf(t1[k], Wl2[k * NACT + t], a2);
    out[g * NACT + t] = a2;
  }
}

extern "C" void kernel_launch(void* const* d_in, const int* in_sizes, int n_in,
                              void* d_out, int out_size, void* d_ws, size_t ws_size,
                              hipStream_t stream) {
  const float* x    = (const float*)d_in[0];
  const int*   ei   = (const int*)d_in[1];
  const int*   batch= (const int*)d_in[2];
  const float* W1   = (const float*)d_in[3];
  const float* b1   = (const float*)d_in[4];
  const float* W2   = (const float*)d_in[5];
  const float* b2   = (const float*)d_in[6];
  const float* Wl1  = (const float*)d_in[7];
  const float* bl1  = (const float*)d_in[8];
  const float* Wl2  = (const float*)d_in[9];
  const float* bl2  = (const float*)d_in[10];
  float* out = (float*)d_out;

  const int* srcp = ei;            // edge_index[0]
  const int* dstp = ei + N_EDGES;  // edge_index[1]

  // workspace bump allocator (512B aligned); zero-region first.
  char* base = (char*)d_ws;
  size_t off = 0;
  auto alloc = [&](size_t bytes) -> void* {
    void* p = base + off;
    off += (bytes + 511) & ~(size_t)511;
    return p;
  };
  int*   cnt    = (int*)alloc((size_t)N_NODES * 4);
  int*   ovfc   = (int*)alloc(4);
  float* gsum   = (float*)alloc((size_t)NGRAPH * NFEAT * 4);
  size_t zspan  = off;  // everything above must start zeroed
  float* dinv   = (float*)alloc((size_t)N_NODES * 4);
  float* invcnt = (float*)alloc((size_t)NGRAPH * 4);
  int*   elist  = (int*)alloc((size_t)N_NODES * ECAP * 4);
  int*   ovf    = (int*)alloc((size_t)OVF_CAP * 2 * 4);
  unsigned short* Wt1 = (unsigned short*)alloc((size_t)NFEAT * NFEAT * 2);
  unsigned short* Wt2 = (unsigned short*)alloc((size_t)NFEAT * NFEAT * 2);
  unsigned short* A = (unsigned short*)alloc((size_t)N_NODES * NFEAT * 2); // bf16 h
  float* B      = (float*)alloc((size_t)N_NODES * NFEAT * 4);              // agg out

  hipMemsetAsync(d_ws, 0, zspan, stream);

  const int EB = (N_EDGES + 255) / 256;   // 6250
  const int NB = (N_NODES + 255) / 256;   // 391
  const int GB = (N_NODES + 63) / 64;     // 1563 gemm blocks

  scatter_kernel<<<EB, 256, 0, stream>>>(srcp, dstp, cnt, elist, ovfc, ovf);
  dinv_kernel<<<NB, 256, 0, stream>>>(cnt, dinv);
  wt_kernel<<<NFEAT * NFEAT / 256, 256, 0, stream>>>(W1, Wt1);
  wt_kernel<<<NFEAT * NFEAT / 256, 256, 0, stream>>>(W2, Wt2);

  // layer 1: A(bf16) = x @ W1 ; B = agg(A) + selfloop + b1 (relu deferred to gemm2)
  gemm_mfma_kernel<<<GB, 256, 0, stream>>>(x, Wt1, A, 0);
  agg_kernel<<<N_NODES / 4, 256, 0, stream>>>((const __hip_bfloat162*)A, elist, cnt, dinv, b1, B);
  ovf_kernel<<<64, 128, 0, stream>>>((const __hip_bfloat16*)A, ovf, ovfc, dinv, B);

  // layer 2: A(bf16) = relu(B) @ W2 ; B = agg(A) + selfloop + b2 (relu at pool)
  gemm_mfma_kernel<<<GB, 256, 0, stream>>>(B, Wt2, A, 1);
  agg_kernel<<<N_NODES / 4, 256, 0, stream>>>((const __hip_bfloat162*)A, elist, cnt, dinv, b2, B);
  ovf_kernel<<<64, 128, 0, stream>>>((const __hip_bfloat16*)A, ovf, ovfc, dinv, B);

  // pool + head
  gcnt_kernel<<<1, 256, 0, stream>>>(batch, invcnt);
  pool_kernel<<<(N_NODES + PCHUNK - 1) / PCHUNK, 64, 0, stream>>>(B, batch, gsum);
  mlp_kernel<<<NGRAPH, 128, 0, stream>>>(gsum, invcnt, Wl1, bl1, Wl2, bl2, out);
}